// Round 3
// baseline (69.986 us; speedup 1.0000x reference)
//
#include <hip/hip_runtime.h>

// PointPillarsScatter: scatter (B,P,C) pillar features into a (B,C,NX,NY) BEV grid.
// Duplicate cells: reference (numpy/XLA scatter-set) is last-write-wins over the
// flattened (B*P) update order => highest p wins per cell. We reproduce that
// deterministically with atomicMax on a per-cell winner-index buffer, then gather.

#define NXD 496
#define NYD 496
#define CD  64
#define BD  4
#define PD  12000
#define NXNY (NXD * NYD)

// Phase 2: each valid pillar claims its cell with atomicMax(p) -> last-wins.
__global__ void pp_scatter_idx(const int* __restrict__ coords,
                               int* __restrict__ winner) {
    int tid = blockIdx.x * blockDim.x + threadIdx.x;
    if (tid >= BD * PD) return;
    int b = tid / PD;
    int p = tid - b * PD;
    int x = coords[tid * 3 + 1];
    int y = coords[tid * 3 + 2];
    bool valid = (x + y > 0) && (x >= 0) && (x < NXD) && (y >= 0) && (y < NYD);
    if (valid) {
        atomicMax(&winner[b * NXNY + x * NYD + y], p);
    }
}

// Phase 3: one thread per 4 consecutive y-cells of one (b,c,x) row.
// Coalesced int4 winner read (winner buffer is 3.9 MB -> L2/LLC resident across
// the 64 channel passes), sparse scalar feature gather (features are 12 MB,
// L2-resident), coalesced float4 output write. Empty cells write zeros, which
// also serves as the output zero-init (harness poisons d_out).
__global__ void pp_gather_out(const float* __restrict__ feats,
                              const int* __restrict__ winner,
                              float* __restrict__ out) {
    const int NY4 = NYD / 4;                       // 124
    const int total4 = BD * CD * NXD * NY4;        // 15,745,024
    int tid = blockIdx.x * blockDim.x + threadIdx.x;
    if (tid >= total4) return;

    int y4 = tid % NY4;
    int r  = tid / NY4;
    int x  = r % NXD;  r /= NXD;
    int c  = r % CD;
    int b  = r / CD;

    const int4 w = *reinterpret_cast<const int4*>(
        &winner[b * NXNY + x * NYD + y4 * 4]);

    float4 v = make_float4(0.f, 0.f, 0.f, 0.f);
    if (w.x >= 0) v.x = feats[((size_t)(b * PD + w.x)) * CD + c];
    if (w.y >= 0) v.y = feats[((size_t)(b * PD + w.y)) * CD + c];
    if (w.z >= 0) v.z = feats[((size_t)(b * PD + w.z)) * CD + c];
    if (w.w >= 0) v.w = feats[((size_t)(b * PD + w.w)) * CD + c];

    // Output linear layout (b,c,x,y): tid*4 is exactly the element offset.
    reinterpret_cast<float4*>(out)[tid] = v;
}

extern "C" void kernel_launch(void* const* d_in, const int* in_sizes, int n_in,
                              void* d_out, int out_size, void* d_ws, size_t ws_size,
                              hipStream_t stream) {
    const float* feats  = (const float*)d_in[0];   // (B,P,C) fp32
    const int*   coords = (const int*)d_in[1];     // (B,P,3) int32
    float*       out    = (float*)d_out;           // (B,C,NX,NY) fp32
    int*         winner = (int*)d_ws;              // B*NX*NY int32 = 3,936,256 B

    const size_t winner_bytes = (size_t)BD * NXNY * sizeof(int);

    // 0xFF bytes -> int32 value -1 ("empty"). hipMemsetAsync is graph-capture safe.
    hipMemsetAsync(winner, 0xFF, winner_bytes, stream);

    // Phase 2: 48,000 pillars.
    pp_scatter_idx<<<(BD * PD + 255) / 256, 256, 0, stream>>>(coords, winner);

    // Phase 3: 15,745,024 float4 threads -> 61,504 blocks of 256.
    const int total4 = BD * CD * NXD * (NYD / 4);
    pp_gather_out<<<(total4 + 255) / 256, 256, 0, stream>>>(feats, winner, out);
}

// Round 4
// 53.030 us; speedup vs baseline: 1.3198x; 1.3198x over previous
//
#include <hip/hip_runtime.h>

// PointPillarsScatter: scatter (B,P,C) pillar features into a (B,C,NX,NY) BEV grid.
// Duplicate cells: reference scatter-set is last-write-wins over flattened (B*P)
// order => highest p wins per cell. Reproduced deterministically via atomicMax
// on a per-cell winner-index buffer, then a channel-blocked gather.

#define NXD 496
#define NYD 496
#define CD  64
#define BD  4
#define PD  12000
#define NXNY (NXD * NYD)
#define NY4 (NYD / 4)      // 124
#define CBLK 16            // channels per thread (one 64B feats cacheline)
#define NCB (CD / CBLK)    // 4 channel-blocks

// Phase 2: each valid pillar claims its cell with atomicMax(p) -> last-wins.
__global__ void pp_scatter_idx(const int* __restrict__ coords,
                               int* __restrict__ winner) {
    int tid = blockIdx.x * blockDim.x + threadIdx.x;
    if (tid >= BD * PD) return;
    int b = tid / PD;
    int x = coords[tid * 3 + 1];
    int y = coords[tid * 3 + 2];
    bool valid = (x + y > 0) && (x >= 0) && (x < NXD) && (y >= 0) && (y < NYD);
    if (valid) {
        int p = tid - b * PD;
        atomicMax(&winner[b * NXNY + x * NYD + y], p);
    }
}

// Phase 3: one thread per {4 consecutive y-cells} x {16-channel block}.
// - 1 coalesced int4 winner read (winner read only NCB=4 times total -> L2-hit)
// - per occupied cell: 4 aligned float4 feats loads = the cell's full 64B
//   channel-slab; across the 4 c-blocks each pillar row is read exactly once
// - 16 coalesced float4 output stores (adjacent lanes -> adjacent y)
// Empty cells store zeros (doubles as output zero-init over poisoned d_out).
__global__ void pp_gather_out(const float* __restrict__ feats,
                              const int* __restrict__ winner,
                              float* __restrict__ out) {
    const int total = BD * NCB * NXD * NY4;        // 984,064
    int tid = blockIdx.x * blockDim.x + threadIdx.x;
    if (tid >= total) return;

    int y4 = tid % NY4;
    int r  = tid / NY4;
    int x  = r % NXD;  r /= NXD;
    int cb = r % NCB;
    int b  = r / NCB;

    const int4 w = *reinterpret_cast<const int4*>(
        &winner[b * NXNY + x * NYD + y4 * 4]);
    const int wa[4] = { w.x, w.y, w.z, w.w };

    float f[4][CBLK] = {};   // [cell][channel] — fully unrolled, stays in VGPRs

#pragma unroll
    for (int j = 0; j < 4; ++j) {
        if (wa[j] >= 0) {
            const float4* src = reinterpret_cast<const float4*>(
                feats + ((size_t)(b * PD + wa[j])) * CD + cb * CBLK);
            float4 a0 = src[0], a1 = src[1], a2 = src[2], a3 = src[3];
            f[j][0]  = a0.x; f[j][1]  = a0.y; f[j][2]  = a0.z; f[j][3]  = a0.w;
            f[j][4]  = a1.x; f[j][5]  = a1.y; f[j][6]  = a1.z; f[j][7]  = a1.w;
            f[j][8]  = a2.x; f[j][9]  = a2.y; f[j][10] = a2.z; f[j][11] = a2.w;
            f[j][12] = a3.x; f[j][13] = a3.y; f[j][14] = a3.z; f[j][15] = a3.w;
        }
    }

    // out[(b, cb*16 + c, x, y4*4 .. +3)], channel stride = NXNY floats.
    float* obase = out + (((size_t)(b * CD + cb * CBLK) * NXD + x) * NYD + y4 * 4);
#pragma unroll
    for (int c = 0; c < CBLK; ++c) {
        float4 v = make_float4(f[0][c], f[1][c], f[2][c], f[3][c]);
        *reinterpret_cast<float4*>(obase + (size_t)c * NXNY) = v;
    }
}

extern "C" void kernel_launch(void* const* d_in, const int* in_sizes, int n_in,
                              void* d_out, int out_size, void* d_ws, size_t ws_size,
                              hipStream_t stream) {
    const float* feats  = (const float*)d_in[0];   // (B,P,C) fp32
    const int*   coords = (const int*)d_in[1];     // (B,P,3) int32
    float*       out    = (float*)d_out;           // (B,C,NX,NY) fp32
    int*         winner = (int*)d_ws;              // B*NX*NY int32 = 3,936,256 B

    const size_t winner_bytes = (size_t)BD * NXNY * sizeof(int);

    // 0xFF bytes -> int32 -1 ("empty"). Graph-capture safe.
    hipMemsetAsync(winner, 0xFF, winner_bytes, stream);

    pp_scatter_idx<<<(BD * PD + 255) / 256, 256, 0, stream>>>(coords, winner);

    const int total = BD * NCB * NXD * NY4;        // 984,064 threads
    pp_gather_out<<<(total + 255) / 256, 256, 0, stream>>>(feats, winner, out);
}